// Round 4
// baseline (1532.880 us; speedup 1.0000x reference)
//
#include <hip/hip_runtime.h>
#include <hip/hip_bf16.h>
#include <cstdint>
#include <cstddef>

// ---------------------------------------------------------------------------
// GCNPool fused pipeline, MI355X/gfx950.  B=8, C=32, N=4000 (pad 4096), T=12.
// Round 4: deep-pipelined GEMM (tile 96x512, grid=256=1/CU, BK=32, 3-buffer
// LDS, counted vmcnt, conflict-free [g][row][16B] LDS layout, setprio); k_m1
// latency fix (768 blocks + atomicAdd).
// ---------------------------------------------------------------------------

typedef __attribute__((ext_vector_type(8))) short s16x8;
typedef __attribute__((ext_vector_type(4))) short s16x4;
typedef __attribute__((ext_vector_type(4))) float f32x4;

#define DEVFN __device__ __forceinline__

DEVFN void gload16(const void* g, void* l) {
  __builtin_amdgcn_global_load_lds((const __attribute__((address_space(1))) unsigned int*)g,
                                   (__attribute__((address_space(3))) unsigned int*)l, 16, 0, 0);
}

DEVFN unsigned short f2bf(float f) {  // round-to-nearest-even f32 -> bf16
  union { float f; unsigned int u; } v; v.f = f;
  unsigned int u = v.u;
  return (unsigned short)((u + 0x7fffu + ((u >> 16) & 1u)) >> 16);
}

// ---------------------------------------------------------------------------
// x (B,C,4000,12) f32 -> Xt[col=b*384+l*32+c][v 4096] bf16  (GEMM1 P operand)
//                     -> Scat[(b*4000+v)*12+l][224] slice j=0 (cols 0..31)
// ---------------------------------------------------------------------------
__global__ void k_transpose(const float* __restrict__ x,
                            unsigned short* __restrict__ Xt,
                            unsigned short* __restrict__ Scat) {
  __shared__ float ldsT[32 * 417];   // [c]*417 + vv*13 + l
  int v0 = blockIdx.x * 32;
  int b = blockIdx.y;
  int tid = threadIdx.x;
  for (int i = tid; i < 1024; i += 256) {
    int c = i >> 5, vv = i & 31;
    const float* src = x + ((size_t)(b * 32 + c) * 4000 + v0 + vv) * 12;
    f32x4 a0 = *(const f32x4*)(src);
    f32x4 a1 = *(const f32x4*)(src + 4);
    f32x4 a2 = *(const f32x4*)(src + 8);
    float* d = ldsT + c * 417 + vv * 13;
    d[0] = a0.x; d[1] = a0.y; d[2] = a0.z; d[3] = a0.w;
    d[4] = a1.x; d[5] = a1.y; d[6] = a1.z; d[7] = a1.w;
    d[8] = a2.x; d[9] = a2.y; d[10] = a2.z; d[11] = a2.w;
  }
  __syncthreads();
  for (int unit = tid; unit < 384; unit += 256) {
    int l = unit >> 5, c = unit & 31;
    alignas(16) unsigned short tmp[32];
#pragma unroll
    for (int vv = 0; vv < 32; ++vv) tmp[vv] = f2bf(ldsT[c * 417 + vv * 13 + l]);
    unsigned short* dst = Xt + (size_t)(b * 384 + l * 32 + c) * 4096 + v0;
#pragma unroll
    for (int j = 0; j < 4; ++j) *(s16x8*)(dst + j * 8) = *(const s16x8*)(tmp + j * 8);
  }
  for (int unit = tid; unit < 384; unit += 256) {
    int l = unit >> 5, vv = unit & 31;
    alignas(16) unsigned short tmp[32];
#pragma unroll
    for (int c = 0; c < 32; ++c) tmp[c] = f2bf(ldsT[c * 417 + vv * 13 + l]);
    unsigned short* dst = Scat + ((size_t)(b * 4000 + v0 + vv) * 12 + l) * 224;
#pragma unroll
    for (int j = 0; j < 4; ++j) *(s16x8*)(dst + j * 8) = *(const s16x8*)(tmp + j * 8);
  }
}

// A (4000,4000) f32 -> A_bf[4096][4096] bf16, zero-padded rows/cols.
__global__ void k_castA(const float* __restrict__ A, unsigned short* __restrict__ Abf) {
  int idx = blockIdx.x * 256 + threadIdx.x;
  int r = idx >> 10;
  int c4 = (idx & 1023) << 2;
  alignas(8) unsigned short o[4] = {0, 0, 0, 0};
  if (r < 4000 && c4 < 4000) {
    f32x4 v = *(const f32x4*)(A + (size_t)r * 4000 + c4);
    o[0] = f2bf(v.x); o[1] = f2bf(v.y); o[2] = f2bf(v.z); o[3] = f2bf(v.w);
  }
  *(s16x4*)(Abf + (size_t)r * 4096 + c4) = *(const s16x4*)o;
}

// mlp_w (64,224,1,3) f32 -> Wcat[oc][kt*224+ic] bf16 (t-independent)
__global__ void k_wcat(const float* __restrict__ mlp_w, unsigned short* __restrict__ Wcat) {
  int i = blockIdx.x * 256 + threadIdx.x;
  if (i >= 64 * 672) return;
  int oc = i / 672, k = i % 672;
  int kt = k / 224, ic = k % 224;
  Wcat[i] = f2bf(mlp_w[((size_t)oc * 224 + ic) * 3 + kt]);
}

// ---------------------------------------------------------------------------
// C[m][n] = sum_k P[m][k] * Q[n][k], bf16, K=4096, M=3072 (col-dim), N=4096
// (node-dim).  Tile 96x512, 8 waves (1x8), BK=32, 3 LDS buffers, counted
// vmcnt pipeline.  LDS layout per tile: A[g][96][16B] + B[g][512][16B].
// Epilogue: LDS repack (2 n-halves) -> C1[m][4096] (if WRITE_C1) + Scat slice.
// GEMM1: P=Xt, Q=Abf.  GEMM2: P=Y1t, Q=Abf (C' = x2 transposed -> same decode).
// ---------------------------------------------------------------------------
#define GBUF 38912

template <int WRITE_C1>
__global__ __launch_bounds__(512, 1)
void k_gemm(const unsigned short* __restrict__ P, const unsigned short* __restrict__ Q,
            unsigned short* __restrict__ C1, unsigned short* __restrict__ Scat, int jcol) {
  extern __shared__ char smem[];    // 3 * GBUF = 116736 bytes
  int tid = threadIdx.x;
  int w = tid >> 6, lane = tid & 63;
  int lr = lane & 15, g = lane >> 4;
  int bid = blockIdx.x;
  int m0 = (bid >> 3) * 96;         // col-dim tile
  int n0 = (bid & 7) * 512;         // node-dim tile; XCD = bid%8 = n-panel

  // staging sources (advance by 64B per K-tile)
  const char* gsrcA = nullptr;
  if (w < 6) {
    int ga = tid / 96, ra = tid - ga * 96;
    gsrcA = (const char*)P + (size_t)(m0 + ra) * 8192 + ga * 16;
  }
  const char* gsrcB = (const char*)Q + (size_t)(n0 + tid) * 8192;

  f32x4 acc[6][4] = {};

  // prologue: stage tiles 0 (buf0) and 1 (buf1)
  {
    if (w < 6) gload16(gsrcA, smem + tid * 16);
#pragma unroll
    for (int cc = 0; cc < 4; ++cc)
      gload16(gsrcB + cc * 16, smem + 6144 + cc * 8192 + tid * 16);
    if (w < 6) gload16(gsrcA + 64, smem + GBUF + tid * 16);
#pragma unroll
    for (int cc = 0; cc < 4; ++cc)
      gload16(gsrcB + 64 + cc * 16, smem + GBUF + 6144 + cc * 8192 + tid * 16);
  }

  int cur = 0, stg = 2;
#pragma unroll 1
  for (int kt = 0; kt < 128; ++kt) {
    // boundary: by FIFO retire order, leaving the newest tile (5 or 4 loads)
    // in flight guarantees tile kt has fully landed.
    if (kt == 127)      asm volatile("s_waitcnt vmcnt(0)" ::: "memory");
    else if (w < 6)     asm volatile("s_waitcnt vmcnt(5)" ::: "memory");
    else                asm volatile("s_waitcnt vmcnt(4)" ::: "memory");
    __builtin_amdgcn_s_barrier();

    // stage tile kt+2 into the buffer freed one iteration ago
    if (kt <= 125) {
      char* sb = smem + stg * GBUF;
      const char* ga2 = gsrcA + kt * 64 + 128;
      const char* gb2 = gsrcB + kt * 64 + 128;
      if (w < 6) gload16(ga2, sb + tid * 16);
      gload16(gb2,      sb + 6144  + tid * 16);
      gload16(gb2 + 16, sb + 14336 + tid * 16);
      gload16(gb2 + 32, sb + 22528 + tid * 16);
      gload16(gb2 + 48, sb + 30720 + tid * 16);
    }

    const char* bc = smem + cur * GBUF;
    const char* aB = bc + g * 1536 + lr * 16;
    const char* bB = bc + 6144 + g * 8192 + (w * 64 + lr) * 16;

    // phase 0: B frags + A frags 0-2, 12 MFMA
    s16x8 b0 = *(const s16x8*)(bB);
    s16x8 b1 = *(const s16x8*)(bB + 256);
    s16x8 b2 = *(const s16x8*)(bB + 512);
    s16x8 b3 = *(const s16x8*)(bB + 768);
    s16x8 a0 = *(const s16x8*)(aB);
    s16x8 a1 = *(const s16x8*)(aB + 256);
    s16x8 a2 = *(const s16x8*)(aB + 512);
    __builtin_amdgcn_s_barrier();
    __builtin_amdgcn_s_setprio(1);
    acc[0][0] = __builtin_amdgcn_mfma_f32_16x16x32_bf16(a0, b0, acc[0][0], 0, 0, 0);
    acc[0][1] = __builtin_amdgcn_mfma_f32_16x16x32_bf16(a0, b1, acc[0][1], 0, 0, 0);
    acc[0][2] = __builtin_amdgcn_mfma_f32_16x16x32_bf16(a0, b2, acc[0][2], 0, 0, 0);
    acc[0][3] = __builtin_amdgcn_mfma_f32_16x16x32_bf16(a0, b3, acc[0][3], 0, 0, 0);
    acc[1][0] = __builtin_amdgcn_mfma_f32_16x16x32_bf16(a1, b0, acc[1][0], 0, 0, 0);
    acc[1][1] = __builtin_amdgcn_mfma_f32_16x16x32_bf16(a1, b1, acc[1][1], 0, 0, 0);
    acc[1][2] = __builtin_amdgcn_mfma_f32_16x16x32_bf16(a1, b2, acc[1][2], 0, 0, 0);
    acc[1][3] = __builtin_amdgcn_mfma_f32_16x16x32_bf16(a1, b3, acc[1][3], 0, 0, 0);
    acc[2][0] = __builtin_amdgcn_mfma_f32_16x16x32_bf16(a2, b0, acc[2][0], 0, 0, 0);
    acc[2][1] = __builtin_amdgcn_mfma_f32_16x16x32_bf16(a2, b1, acc[2][1], 0, 0, 0);
    acc[2][2] = __builtin_amdgcn_mfma_f32_16x16x32_bf16(a2, b2, acc[2][2], 0, 0, 0);
    acc[2][3] = __builtin_amdgcn_mfma_f32_16x16x32_bf16(a2, b3, acc[2][3], 0, 0, 0);
    __builtin_amdgcn_s_setprio(0);

    // phase 1: A frags 3-5, 12 MFMA
    s16x8 a3 = *(const s16x8*)(aB + 768);
    s16x8 a4 = *(const s16x8*)(aB + 1024);
    s16x8 a5 = *(const s16x8*)(aB + 1280);
    __builtin_amdgcn_s_barrier();
    __builtin_amdgcn_s_setprio(1);
    acc[3][0] = __builtin_amdgcn_mfma_f32_16x16x32_bf16(a3, b0, acc[3][0], 0, 0, 0);
    acc[3][1] = __builtin_amdgcn_mfma_f32_16x16x32_bf16(a3, b1, acc[3][1], 0, 0, 0);
    acc[3][2] = __builtin_amdgcn_mfma_f32_16x16x32_bf16(a3, b2, acc[3][2], 0, 0, 0);
    acc[3][3] = __builtin_amdgcn_mfma_f32_16x16x32_bf16(a3, b3, acc[3][3], 0, 0, 0);
    acc[4][0] = __builtin_amdgcn_mfma_f32_16x16x32_bf16(a4, b0, acc[4][0], 0, 0, 0);
    acc[4][1] = __builtin_amdgcn_mfma_f32_16x16x32_bf16(a4, b1, acc[4][1], 0, 0, 0);
    acc[4][2] = __builtin_amdgcn_mfma_f32_16x16x32_bf16(a4, b2, acc[4][2], 0, 0, 0);
    acc[4][3] = __builtin_amdgcn_mfma_f32_16x16x32_bf16(a4, b3, acc[4][3], 0, 0, 0);
    acc[5][0] = __builtin_amdgcn_mfma_f32_16x16x32_bf16(a5, b0, acc[5][0], 0, 0, 0);
    acc[5][1] = __builtin_amdgcn_mfma_f32_16x16x32_bf16(a5, b1, acc[5][1], 0, 0, 0);
    acc[5][2] = __builtin_amdgcn_mfma_f32_16x16x32_bf16(a5, b2, acc[5][2], 0, 0, 0);
    acc[5][3] = __builtin_amdgcn_mfma_f32_16x16x32_bf16(a5, b3, acc[5][3], 0, 0, 0);
    __builtin_amdgcn_s_setprio(0);

    cur = (cur == 2) ? 0 : cur + 1;
    stg = (stg == 2) ? 0 : stg + 1;
  }

  // epilogue: repack via LDS [96][264], two n-halves of 256
  unsigned short* eld = (unsigned short*)smem;
  int rb = g * 4;
  int bdec = m0 / 384;
  int lb = (m0 % 384) >> 5;
#pragma unroll
  for (int h = 0; h < 2; ++h) {
    asm volatile("s_waitcnt lgkmcnt(0)" ::: "memory");
    __builtin_amdgcn_s_barrier();
    if ((w >> 2) == h) {
      int nbase = (w & 3) * 64 + lr;
#pragma unroll
      for (int fm = 0; fm < 6; ++fm)
#pragma unroll
        for (int fn = 0; fn < 4; ++fn)
#pragma unroll
          for (int r = 0; r < 4; ++r)
            eld[(fm * 16 + rb + r) * 264 + nbase + fn * 16] = f2bf(acc[fm][fn][r]);
    }
    asm volatile("s_waitcnt lgkmcnt(0)" ::: "memory");
    __builtin_amdgcn_s_barrier();
    if (WRITE_C1 && tid < 384) {
      int row = tid >> 2, q = tid & 3;
      unsigned short* dst = C1 + (size_t)(m0 + row) * 4096 + n0 + h * 256 + q * 64;
      const unsigned short* sp = eld + row * 264 + q * 64;
#pragma unroll
      for (int j2 = 0; j2 < 8; ++j2) *(s16x8*)(dst + j2 * 8) = *(const s16x8*)(sp + j2 * 8);
    }
#pragma unroll
    for (int u = 0; u < 2; ++u) {
      int unit = u * 512 + tid;
      if (unit < 768) {
        int lg = unit >> 8, nl = unit & 255;
        int node = n0 + h * 256 + nl;
        if (node < 4000) {
          alignas(16) unsigned short tmp[32];
#pragma unroll
          for (int c = 0; c < 32; ++c) tmp[c] = eld[(lg * 32 + c) * 264 + nl];
          unsigned short* d2 = Scat + ((size_t)(bdec * 4000 + node) * 12 + lb + lg) * 224 + jcol;
#pragma unroll
          for (int j2 = 0; j2 < 4; ++j2) *(s16x8*)(d2 + j2 * 8) = *(const s16x8*)(tmp + j2 * 8);
        }
      }
    }
  }
}

// ---------------------------------------------------------------------------
// mlp GEMM: OUT[oc=64][bn] = sum_{k<672} Wcat[oc][k] * Scat[bn*12+t][k..], then
// gate tanh*sigmoid -> G[b][t][c][4096] f32.  Tile 64x256, 4 waves of 64x64.
// ---------------------------------------------------------------------------
__global__ __launch_bounds__(256, 2)
void k_mlp(const unsigned short* __restrict__ Wcat, const unsigned short* __restrict__ Scat,
           const float* __restrict__ mlp_b, float* __restrict__ G) {
  __shared__ unsigned short lds[2048 + 8192];  // Ws[64][32] + Bs[256][32]
  unsigned short* Ws = lds;
  unsigned short* Bs = lds + 2048;
  int tid = threadIdx.x;
  int bn0 = blockIdx.x * 256;
  int t = blockIdx.y;      // 0..9
  int w = tid >> 6, lane = tid & 63;
  int lr = lane & 15, lk = (lane >> 4) * 8;
  f32x4 acc[4][4] = {};
  const unsigned short* gw = Wcat + (size_t)(tid >> 2) * 672 + (tid & 3) * 8;
  const unsigned short* gq = Scat + ((size_t)(bn0 + (tid >> 2)) * 12 + t) * 224 + (tid & 3) * 8;
  unsigned short* lw = Ws + tid * 8;
  unsigned short* lq = Bs + tid * 8;
  for (int s = 0; s < 21; ++s) {
    gload16(gw + s * 32, lw);
#pragma unroll
    for (int r = 0; r < 4; ++r)
      gload16(gq + (size_t)r * 64 * 2688 + s * 32, lq + r * 2048);
    __syncthreads();
    s16x8 a[4], bb[4];
#pragma unroll
    for (int f = 0; f < 4; ++f) {
      a[f] = *(const s16x8*)(Ws + (f * 16 + lr) * 32 + lk);
      bb[f] = *(const s16x8*)(Bs + (w * 64 + f * 16 + lr) * 32 + lk);
    }
#pragma unroll
    for (int fm = 0; fm < 4; ++fm)
#pragma unroll
      for (int fn = 0; fn < 4; ++fn)
        acc[fm][fn] = __builtin_amdgcn_mfma_f32_16x16x32_bf16(a[fm], bb[fn], acc[fm][fn], 0, 0, 0);
    __syncthreads();
  }
  int rbase = (lane >> 4) * 4;
#pragma unroll
  for (int fn = 0; fn < 4; ++fn) {
    int bn = bn0 + w * 64 + fn * 16 + lr;
    int b = bn / 4000;
    int n = bn - b * 4000;
    float* gbase = G + (size_t)(b * 10 + t) * 32 * 4096 + n;
#pragma unroll
    for (int fm = 0; fm < 2; ++fm)
#pragma unroll
      for (int r = 0; r < 4; ++r) {
        int c = fm * 16 + rbase + r;
        float v1 = acc[fm][fn][r] + mlp_b[c];
        float v2 = acc[fm + 2][fn][r] + mlp_b[c + 32];
        gbase[(size_t)c * 4096] = tanhf(v1) * (1.0f / (1.0f + __expf(-v2)));
      }
  }
}

// ct1: g6[b][c][n][q] = ct1_b[q] + sum_{l<10} ct1_w[q][l] * G[b][l][c][n]
__global__ void k_ct1(const float* __restrict__ G, const float* __restrict__ ct1_w,
                      const float* __restrict__ ct1_b, float* __restrict__ g6) {
  int idx = blockIdx.x * 256 + threadIdx.x;
  if (idx >= 8 * 32 * 4000) return;
  int n = idx % 4000;
  int c = (idx / 4000) % 32;
  int b = idx / (4000 * 32);
  const float* gp = G + ((size_t)(b * 10) * 32 + c) * 4096 + n;
  float v[10];
#pragma unroll
  for (int l = 0; l < 10; ++l) v[l] = gp[(size_t)l * 32 * 4096];
  float* o = g6 + (size_t)idx * 6;
#pragma unroll
  for (int q = 0; q < 6; ++q) {
    float a = ct1_b[q];
#pragma unroll
    for (int l = 0; l < 10; ++l) a += ct1_w[q * 10 + l] * v[l];
    o[q] = a;
  }
}

// f1[b][t][n] = sum_c c1[c] * g6[b][c][n][t]
__global__ void k_f1(const float* __restrict__ g6, const float* __restrict__ c1,
                     float* __restrict__ f1) {
  int idx = blockIdx.x * 128 + threadIdx.x;
  if (idx >= 8 * 4000) return;
  int n = idx % 4000, b = idx / 4000;
  float acc[6] = {};
  const float* gp = g6 + ((size_t)b * 32 * 4000 + n) * 6;
  for (int c = 0; c < 32; ++c) {
    float wv = c1[c];
    const float* p = gp + (size_t)c * 4000 * 6;
#pragma unroll
    for (int t = 0; t < 6; ++t) acc[t] += wv * p[t];
  }
  for (int t = 0; t < 6; ++t) f1[((size_t)b * 6 + t) * 4000 + n] = acc[t];
}

// f2[b][c][t] = sum_n c2[n] * g6[b][c][n][t]
__global__ void k_f2(const float* __restrict__ g6, const float* __restrict__ c2,
                     float* __restrict__ f2) {
  __shared__ float red[256 * 6];
  int bc = blockIdx.x;
  int tid = threadIdx.x;
  float acc[6] = {};
  const float* gp = g6 + (size_t)bc * 4000 * 6;
  for (int n = tid; n < 4000; n += 256) {
    float wv = c2[n];
#pragma unroll
    for (int t = 0; t < 6; ++t) acc[t] += wv * gp[(size_t)n * 6 + t];
  }
  for (int t = 0; t < 6; ++t) red[tid * 6 + t] = acc[t];
  __syncthreads();
  for (int s = 128; s > 0; s >>= 1) {
    if (tid < s)
      for (int t = 0; t < 6; ++t) red[tid * 6 + t] += red[(tid + s) * 6 + t];
    __syncthreads();
  }
  if (tid < 6) f2[bc * 6 + tid] = red[tid];
}

// m1[b][t][c] += sum over n-chunk of f1[b][t][n] * tat_w[n][c]; grid (48,16)
__global__ void k_m1(const float* __restrict__ f1, const float* __restrict__ tw,
                     float* __restrict__ m1) {
  __shared__ float red[8][32];
  int bt = blockIdx.x;
  int nc = blockIdx.y;
  int tid = threadIdx.x;
  int c = tid & 31, gi = tid >> 5;
  float acc = 0.f;
  const float* fp = f1 + (size_t)bt * 4000 + nc * 250;
  const float* twp = tw + ((size_t)nc * 250) * 32 + c;
  for (int n = gi; n < 250; n += 8) acc += fp[n] * twp[n * 32];
  red[gi][c] = acc;
  __syncthreads();
  if (tid < 32) {
    float s = 0.f;
#pragma unroll
    for (int gg = 0; gg < 8; ++gg) s += red[gg][c];
    atomicAdd(&m1[(size_t)bt * 32 + c], s);
  }
}

// logits -> sigmoid -> tat_v mix -> BN1 -> softmax -> coefs[b][t][q]
__global__ void k_att(const float* __restrict__ m1, const float* __restrict__ f2,
                      const float* __restrict__ bias, const float* __restrict__ tv,
                      const float* __restrict__ g1, const float* __restrict__ b1,
                      float* __restrict__ coefs) {
  __shared__ float sig[48 * 6], lgs[48 * 6], mu[6], iv[6];
  int tid = threadIdx.x;
  int b = tid / 6, t = tid % 6;
  if (tid < 48) {
    for (int s = 0; s < 6; ++s) {
      float a = bias[t * 6 + s];
      for (int c = 0; c < 32; ++c)
        a += m1[((size_t)b * 6 + t) * 32 + c] * f2[((size_t)b * 32 + c) * 6 + s];
      sig[tid * 6 + s] = 1.0f / (1.0f + __expf(-a));
    }
  }
  __syncthreads();
  if (tid < 48) {
    for (int q = 0; q < 6; ++q) {
      float a = 0.f;
      for (int s = 0; s < 6; ++s) a += tv[t * 6 + s] * sig[(b * 6 + s) * 6 + q];
      lgs[tid * 6 + q] = a;
    }
  }
  __syncthreads();
  if (tid < 6) {
    float s = 0, s2 = 0;
    for (int r = 0; r < 48; ++r) { float v = lgs[r * 6 + tid]; s += v; s2 += v * v; }
    float m = s / 48.f;
    mu[tid] = m;
    iv[tid] = rsqrtf(s2 / 48.f - m * m + 1e-5f);
  }
  __syncthreads();
  if (tid < 48) {
    float v[6], mx = -1e30f;
    for (int q = 0; q < 6; ++q) {
      v[q] = (lgs[tid * 6 + q] - mu[q]) * iv[q] * g1[q] + b1[q];
      mx = fmaxf(mx, v[q]);
    }
    float s = 0;
    for (int q = 0; q < 6; ++q) { v[q] = __expf(v[q] - mx); s += v[q]; }
    float inv = 1.0f / s;
    for (int q = 0; q < 6; ++q) coefs[tid * 6 + q] = v[q] * inv;
  }
}

// y = attention-mix(g6) + conv1(x)[...,6:] -> out (pre-BN2)
__global__ void k_final1(const float* __restrict__ x, const float* __restrict__ cw,
                         const float* __restrict__ cb, const float* __restrict__ g6,
                         const float* __restrict__ coefs, float* __restrict__ out) {
  __shared__ float xt[32 * 8 * 6];
  __shared__ float cwT[1024];
  __shared__ float cfs[36], cbs[32];
  int n0 = blockIdx.x * 8;
  int b = blockIdx.y;
  int tid = threadIdx.x;
  {
    int ci = tid >> 3, seg = tid & 7;
    const float* xp = x + ((size_t)(b * 32 + ci) * 4000 + n0 + seg) * 12 + 6;
#pragma unroll
    for (int q = 0; q < 6; ++q) xt[(ci * 8 + seg) * 6 + q] = xp[q];
  }
  for (int i = tid; i < 1024; i += 256) { int o = i >> 5, ci = i & 31; cwT[ci * 32 + o] = cw[i]; }
  if (tid < 36) cfs[tid] = coefs[b * 36 + tid];
  if (tid < 32) cbs[tid] = cb[tid];
  __syncthreads();
  int nn = tid & 7, c = tid >> 3;
  const float* gp = g6 + ((size_t)(b * 32 + c) * 4000 + n0 + nn) * 6;
  float gv[6];
#pragma unroll
  for (int l = 0; l < 6; ++l) gv[l] = gp[l];
  float y[6];
#pragma unroll
  for (int q = 0; q < 6; ++q) {
    float at = 0.f;
#pragma unroll
    for (int l = 0; l < 6; ++l) at += gv[l] * cfs[q * 6 + l];
    y[q] = at + cbs[c];
  }
  for (int ci = 0; ci < 32; ++ci) {
    float wv = cwT[ci * 32 + c];
#pragma unroll
    for (int q = 0; q < 6; ++q) y[q] += wv * xt[(ci * 8 + nn) * 6 + q];
  }
  float* op = out + ((size_t)(b * 32 + c) * 4000 + n0 + nn) * 6;
#pragma unroll
  for (int q = 0; q < 6; ++q) op[q] = y[q];
}

// per-channel sum/sumsq of out: grid (4, 256), f32x4 + shfl reduce + atomicAdd
__global__ void k_stats(const float* __restrict__ out, float* __restrict__ stats) {
  __shared__ float r1[4], r2[4];
  int bc = blockIdx.y;
  int c = bc & 31;
  int tid = threadIdx.x;
  const float* p = out + (size_t)bc * 24000 + blockIdx.x * 6000;
  float s = 0.f, s2 = 0.f;
  for (int i = tid * 4; i < 6000; i += 1024) {
    f32x4 v = *(const f32x4*)(p + i);
    s  += v.x + v.y + v.z + v.w;
    s2 += v.x * v.x + v.y * v.y + v.z * v.z + v.w * v.w;
  }
#pragma unroll
  for (int off = 32; off > 0; off >>= 1) {
    s  += __shfl_down(s, off);
    s2 += __shfl_down(s2, off);
  }
  int lane = tid & 63, w = tid >> 6;
  if (lane == 0) { r1[w] = s; r2[w] = s2; }
  __syncthreads();
  if (tid == 0) {
    atomicAdd(&stats[c],      r1[0] + r1[1] + r1[2] + r1[3]);
    atomicAdd(&stats[32 + c], r2[0] + r2[1] + r2[2] + r2[3]);
  }
}

__global__ void k_final2(float* __restrict__ out, const float* __restrict__ stats,
                         const float* __restrict__ g2, const float* __restrict__ b2) {
  int idx = (blockIdx.x * 256 + threadIdx.x) * 4;
  if (idx >= 6144000) return;
  int c = (idx / 24000) % 32;
  float mean = stats[c] * (1.0f / 192000.f);
  float var = stats[32 + c] * (1.0f / 192000.f) - mean * mean;
  float sc = rsqrtf(var + 1e-5f) * g2[c];
  float sh = b2[c] - mean * sc;
  f32x4 v = *(f32x4*)(out + idx);
  v.x = v.x * sc + sh; v.y = v.y * sc + sh; v.z = v.z * sc + sh; v.w = v.w * sc + sh;
  *(f32x4*)(out + idx) = v;
}

// ---------------------------------------------------------------------------
extern "C" void kernel_launch(void* const* d_in, const int* in_sizes, int n_in,
                              void* d_out, int out_size, void* d_ws, size_t ws_size,
                              hipStream_t stream) {
  (void)in_sizes; (void)n_in; (void)out_size;
  const float* x       = (const float*)d_in[0];
  const float* A[3]    = {(const float*)d_in[1], (const float*)d_in[2], (const float*)d_in[3]};
  const float* conv1_w = (const float*)d_in[4];
  const float* conv1_b = (const float*)d_in[5];
  const float* mlp_w   = (const float*)d_in[6];
  const float* mlp_b   = (const float*)d_in[7];
  const float* ct1_w   = (const float*)d_in[8];
  const float* ct1_b   = (const float*)d_in[9];
  const float* c1w     = (const float*)d_in[10];
  const float* c2w     = (const float*)d_in[11];
  const float* tw      = (const float*)d_in[12];
  const float* tbias   = (const float*)d_in[13];
  const float* tv      = (const float*)d_in[14];
  const float* bn1g    = (const float*)d_in[15];
  const float* bn1b    = (const float*)d_in[16];
  const float* bn2g    = (const float*)d_in[17];
  const float* bn2b    = (const float*)d_in[18];
  float* out = (float*)d_out;

  char* ws = (char*)d_ws;
  size_t off = 0;
  auto alloc = [&](size_t bytes) { size_t r = off; off += (bytes + 255) & ~(size_t)255; return r; };
  size_t oScat = alloc(172032000);   // [32000*12][224] bf16
  size_t oXt   = alloc(25165824);    // [3072][4096] bf16 ; later g6 (24.576MB f32)
  size_t oA    = alloc(33554432);    // Abf [4096][4096] bf16 ; with oY1t, later G
  size_t oY1t  = alloc(25165824);    // [3072][4096] bf16
  size_t oWcat = alloc(86016);
  size_t oF1 = alloc(768000);
  size_t oF2 = alloc(6144);
  size_t oM1 = alloc(6144);
  size_t oCf = alloc(1152);
  size_t oSt = alloc(256);
  if (ws_size < off) return;  // insufficient scratch -> visible validation failure

  unsigned short* Scat = (unsigned short*)(ws + oScat);
  unsigned short* Xt   = (unsigned short*)(ws + oXt);
  float*          g6   = (float*)(ws + oXt);
  unsigned short* Abf  = (unsigned short*)(ws + oA);
  float*          G    = (float*)(ws + oA);
  unsigned short* Y1t  = (unsigned short*)(ws + oY1t);
  unsigned short* Wcat = (unsigned short*)(ws + oWcat);

  hipFuncSetAttribute((const void*)k_gemm<1>, hipFuncAttributeMaxDynamicSharedMemorySize, 3 * GBUF);
  hipFuncSetAttribute((const void*)k_gemm<0>, hipFuncAttributeMaxDynamicSharedMemorySize, 3 * GBUF);

  hipMemsetAsync(Xt, 0, 25165824, stream);       // v-padding 4000..4095 must be 0
  hipMemsetAsync(ws + oSt, 0, 256, stream);      // stats accumulators
  hipMemsetAsync(ws + oM1, 0, 6144, stream);     // m1 accumulators
  k_transpose<<<dim3(125, 8), 256, 0, stream>>>(x, Xt, Scat);
  k_wcat<<<168, 256, 0, stream>>>(mlp_w, Wcat);
  for (int i = 0; i < 3; ++i) {
    k_castA<<<16384, 256, 0, stream>>>(A[i], Abf);
    // Y1t[col][node] = sum_v Xt[col][v]*Abf[node][v]; Scat j=2i+1
    k_gemm<1><<<256, 512, 3 * GBUF, stream>>>(Xt, Abf, Y1t, Scat, (2 * i + 1) * 32);
    // x2^T[col][node] = sum_v Y1t[col][v]*Abf[node][v]; Scat j=2i+2
    k_gemm<0><<<256, 512, 3 * GBUF, stream>>>(Y1t, Abf, nullptr, Scat, (2 * i + 2) * 32);
  }
  k_mlp<<<dim3(125, 10), 256, 0, stream>>>(Wcat, Scat, mlp_b, G);
  k_ct1<<<4000, 256, 0, stream>>>(G, ct1_w, ct1_b, g6);
  k_f1<<<250, 128, 0, stream>>>(g6, c1w, (float*)(ws + oF1));
  k_f2<<<256, 256, 0, stream>>>(g6, c2w, (float*)(ws + oF2));
  k_m1<<<dim3(48, 16), 256, 0, stream>>>((float*)(ws + oF1), tw, (float*)(ws + oM1));
  k_att<<<1, 64, 0, stream>>>((float*)(ws + oM1), (float*)(ws + oF2), tbias, tv, bn1g, bn1b,
                              (float*)(ws + oCf));
  k_final1<<<dim3(500, 8), 256, 0, stream>>>(x, conv1_w, conv1_b, g6, (float*)(ws + oCf), out);
  k_stats<<<dim3(4, 256), 256, 0, stream>>>(out, (float*)(ws + oSt));
  k_final2<<<6000, 256, 0, stream>>>(out, (float*)(ws + oSt), bn2g, bn2b);
}

// Round 5
// 988.483 us; speedup vs baseline: 1.5507x; 1.5507x over previous
//
#include <hip/hip_runtime.h>
#include <hip/hip_bf16.h>
#include <cstdint>
#include <cstddef>

// ---------------------------------------------------------------------------
// GCNPool fused pipeline, MI355X/gfx950.  B=8, C=32, N=4000 (pad 4096), T=12.
// Round 5: revert GEMM to the proven m97-style 128x128 kernel (round-3, 937 TF;
// the round-4 1-block/CU deep pipeline stalled in barrier lockstep: MfmaUtil
// 18%, 229 us).  Keep round-4's k_m1 latency fix (173 -> ~8 us).
// ---------------------------------------------------------------------------

typedef __attribute__((ext_vector_type(8))) short s16x8;
typedef __attribute__((ext_vector_type(4))) short s16x4;
typedef __attribute__((ext_vector_type(4))) float f32x4;

#define DEVFN __device__ __forceinline__

DEVFN void gload16(const void* g, void* l) {
  __builtin_amdgcn_global_load_lds((const __attribute__((address_space(1))) unsigned int*)g,
                                   (__attribute__((address_space(3))) unsigned int*)l, 16, 0, 0);
}

DEVFN unsigned short f2bf(float f) {  // round-to-nearest-even f32 -> bf16
  union { float f; unsigned int u; } v; v.f = f;
  unsigned int u = v.u;
  return (unsigned short)((u + 0x7fffu + ((u >> 16) & 1u)) >> 16);
}

// ---------------------------------------------------------------------------
// x (B,C,4000,12) f32 -> Xt[col=b*384+l*32+c][v 4096] bf16  (GEMM1 P operand)
//                     -> Scat[(b*4000+v)*12+l][224] slice j=0 (cols 0..31)
// ---------------------------------------------------------------------------
__global__ void k_transpose(const float* __restrict__ x,
                            unsigned short* __restrict__ Xt,
                            unsigned short* __restrict__ Scat) {
  __shared__ float ldsT[32 * 417];   // [c]*417 + vv*13 + l
  int v0 = blockIdx.x * 32;
  int b = blockIdx.y;
  int tid = threadIdx.x;
  for (int i = tid; i < 1024; i += 256) {
    int c = i >> 5, vv = i & 31;
    const float* src = x + ((size_t)(b * 32 + c) * 4000 + v0 + vv) * 12;
    f32x4 a0 = *(const f32x4*)(src);
    f32x4 a1 = *(const f32x4*)(src + 4);
    f32x4 a2 = *(const f32x4*)(src + 8);
    float* d = ldsT + c * 417 + vv * 13;
    d[0] = a0.x; d[1] = a0.y; d[2] = a0.z; d[3] = a0.w;
    d[4] = a1.x; d[5] = a1.y; d[6] = a1.z; d[7] = a1.w;
    d[8] = a2.x; d[9] = a2.y; d[10] = a2.z; d[11] = a2.w;
  }
  __syncthreads();
  for (int unit = tid; unit < 384; unit += 256) {
    int l = unit >> 5, c = unit & 31;
    alignas(16) unsigned short tmp[32];
#pragma unroll
    for (int vv = 0; vv < 32; ++vv) tmp[vv] = f2bf(ldsT[c * 417 + vv * 13 + l]);
    unsigned short* dst = Xt + (size_t)(b * 384 + l * 32 + c) * 4096 + v0;
#pragma unroll
    for (int j = 0; j < 4; ++j) *(s16x8*)(dst + j * 8) = *(const s16x8*)(tmp + j * 8);
  }
  for (int unit = tid; unit < 384; unit += 256) {
    int l = unit >> 5, vv = unit & 31;
    alignas(16) unsigned short tmp[32];
#pragma unroll
    for (int c = 0; c < 32; ++c) tmp[c] = f2bf(ldsT[c * 417 + vv * 13 + l]);
    unsigned short* dst = Scat + ((size_t)(b * 4000 + v0 + vv) * 12 + l) * 224;
#pragma unroll
    for (int j = 0; j < 4; ++j) *(s16x8*)(dst + j * 8) = *(const s16x8*)(tmp + j * 8);
  }
}

// A (4000,4000) f32 -> A_bf[4096][4096] bf16, zero-padded rows/cols.
__global__ void k_castA(const float* __restrict__ A, unsigned short* __restrict__ Abf) {
  int idx = blockIdx.x * 256 + threadIdx.x;
  int r = idx >> 10;
  int c4 = (idx & 1023) << 2;
  alignas(8) unsigned short o[4] = {0, 0, 0, 0};
  if (r < 4000 && c4 < 4000) {
    f32x4 v = *(const f32x4*)(A + (size_t)r * 4000 + c4);
    o[0] = f2bf(v.x); o[1] = f2bf(v.y); o[2] = f2bf(v.z); o[3] = f2bf(v.w);
  }
  *(s16x4*)(Abf + (size_t)r * 4096 + c4) = *(const s16x4*)o;
}

// mlp_w (64,224,1,3) f32 -> Wcat[oc][kt*224+ic] bf16 (t-independent)
__global__ void k_wcat(const float* __restrict__ mlp_w, unsigned short* __restrict__ Wcat) {
  int i = blockIdx.x * 256 + threadIdx.x;
  if (i >= 64 * 672) return;
  int oc = i / 672, k = i % 672;
  int kt = k / 224, ic = k % 224;
  Wcat[i] = f2bf(mlp_w[((size_t)oc * 224 + ic) * 3 + kt]);
}

// ---------------------------------------------------------------------------
// C[m][n] = sum_k P[m][k] * Q[n][k], bf16, K=4096.  128x128 tile, 768 blocks,
// XCD-aware swizzle (768 % 8 == 0 -> simple bijective form).
// MODE 0 (GEMM1, 24 m-tiles x 32 n-tiles): store C1 + Scat (m-decode).
// MODE 1 (GEMM2, 32 m-tiles x 24 n-tiles): store Scat only (n-decode).
// ---------------------------------------------------------------------------
template <int MODE>
__global__ __launch_bounds__(256, 2)
void k_gemm(const unsigned short* __restrict__ P, const unsigned short* __restrict__ Q,
            unsigned short* __restrict__ C1, unsigned short* __restrict__ Scat, int jcol) {
  __shared__ unsigned short lds[128 * 136];
  unsigned short* Ps = lds;          // [128][32]
  unsigned short* Qs = lds + 4096;   // [128][32]
  int tid = threadIdx.x;
  int wid = blockIdx.x;
  int swz = (wid & 7) * 96 + (wid >> 3);     // 768 blocks over 8 XCDs
  int m0, n0;
  if (MODE == 0) { m0 = (swz >> 5) * 128; n0 = (swz & 31) * 128; }
  else           { m0 = (swz / 24) * 128; n0 = (swz % 24) * 128; }
  int w = tid >> 6, lane = tid & 63;
  int wm = (w >> 1) * 64, wn = (w & 1) * 64;
  int lr = lane & 15, lk = (lane >> 4) * 8;
  f32x4 acc[4][4] = {};
  const unsigned short* gp = P + (size_t)(m0 + (tid >> 2)) * 4096 + ((tid & 3) * 8);
  const unsigned short* gq = Q + (size_t)(n0 + (tid >> 2)) * 4096 + ((tid & 3) * 8);
  unsigned short* lp = Ps + tid * 8;
  unsigned short* lq = Qs + tid * 8;
  for (int kt = 0; kt < 128; ++kt) {
    gload16(gp, lp);  gload16(gp + (size_t)64 * 4096, lp + 2048);
    gload16(gq, lq);  gload16(gq + (size_t)64 * 4096, lq + 2048);
    gp += 32; gq += 32;
    __syncthreads();
    s16x8 a[4], b[4];
#pragma unroll
    for (int f = 0; f < 4; ++f) {
      a[f] = *(const s16x8*)(Ps + (wm + f * 16 + lr) * 32 + lk);
      b[f] = *(const s16x8*)(Qs + (wn + f * 16 + lr) * 32 + lk);
    }
#pragma unroll
    for (int fm = 0; fm < 4; ++fm)
#pragma unroll
      for (int fn = 0; fn < 4; ++fn)
        acc[fm][fn] = __builtin_amdgcn_mfma_f32_16x16x32_bf16(a[fm], b[fn], acc[fm][fn], 0, 0, 0);
    __syncthreads();
  }
  // regs -> LDS [128][136]  (C/D: col=lane&15, row=(lane>>4)*4+reg)
#pragma unroll
  for (int fm = 0; fm < 4; ++fm)
#pragma unroll
    for (int fn = 0; fn < 4; ++fn)
#pragma unroll
      for (int r = 0; r < 4; ++r) {
        int mm = wm + fm * 16 + (lane >> 4) * 4 + r;
        int nn = wn + fn * 16 + lr;
        lds[mm * 136 + nn] = f2bf(acc[fm][fn][r]);
      }
  __syncthreads();
  if (MODE == 0) {
    int rr = tid >> 1, half = tid & 1;
    unsigned short* dst = C1 + (size_t)(m0 + rr) * 4096 + n0 + half * 64;
    const unsigned short* srcp = lds + rr * 136 + half * 64;
#pragma unroll
    for (int j = 0; j < 8; ++j) *(s16x8*)(dst + j * 8) = *(const s16x8*)(srcp + j * 8);
    int b = m0 / 384;
    int lbase = (m0 % 384) >> 5;
    for (int unit = tid; unit < 512; unit += 256) {
      int node_l = unit & 127, lg = unit >> 7;
      int node = n0 + node_l;
      if (node < 4000) {
        alignas(16) unsigned short tmp[32];
#pragma unroll
        for (int c = 0; c < 32; ++c) tmp[c] = lds[(lg * 32 + c) * 136 + node_l];
        unsigned short* d2 = Scat + ((size_t)(b * 4000 + node) * 12 + lbase + lg) * 224 + jcol;
#pragma unroll
        for (int j = 0; j < 4; ++j) *(s16x8*)(d2 + j * 8) = *(const s16x8*)(tmp + j * 8);
      }
    }
  } else {
    int b = n0 / 384;
    int lbase = (n0 % 384) >> 5;
    for (int unit = tid; unit < 512; unit += 256) {
      int node_l = unit & 127, lg = unit >> 7;
      int node = m0 + node_l;
      if (node < 4000) {
        alignas(16) unsigned short tmp[32];
        const unsigned short* sp = lds + node_l * 136 + lg * 32;
#pragma unroll
        for (int j = 0; j < 4; ++j) *(s16x8*)(tmp + j * 8) = *(const s16x8*)(sp + j * 8);
        unsigned short* d2 = Scat + ((size_t)(b * 4000 + node) * 12 + lbase + lg) * 224 + jcol;
#pragma unroll
        for (int j = 0; j < 4; ++j) *(s16x8*)(d2 + j * 8) = *(const s16x8*)(tmp + j * 8);
      }
    }
  }
}

// ---------------------------------------------------------------------------
// mlp GEMM: OUT[oc=64][bn] = sum_{k<672} Wcat[oc][k] * Scat[bn*12+t][k..], then
// gate tanh*sigmoid -> G[b][t][c][4096] f32.  Tile 64x256, 4 waves of 64x64.
// ---------------------------------------------------------------------------
__global__ __launch_bounds__(256, 2)
void k_mlp(const unsigned short* __restrict__ Wcat, const unsigned short* __restrict__ Scat,
           const float* __restrict__ mlp_b, float* __restrict__ G) {
  __shared__ unsigned short lds[2048 + 8192];  // Ws[64][32] + Bs[256][32]
  unsigned short* Ws = lds;
  unsigned short* Bs = lds + 2048;
  int tid = threadIdx.x;
  int bn0 = blockIdx.x * 256;
  int t = blockIdx.y;      // 0..9
  int w = tid >> 6, lane = tid & 63;
  int lr = lane & 15, lk = (lane >> 4) * 8;
  f32x4 acc[4][4] = {};
  const unsigned short* gw = Wcat + (size_t)(tid >> 2) * 672 + (tid & 3) * 8;
  const unsigned short* gq = Scat + ((size_t)(bn0 + (tid >> 2)) * 12 + t) * 224 + (tid & 3) * 8;
  unsigned short* lw = Ws + tid * 8;
  unsigned short* lq = Bs + tid * 8;
  for (int s = 0; s < 21; ++s) {
    gload16(gw + s * 32, lw);
#pragma unroll
    for (int r = 0; r < 4; ++r)
      gload16(gq + (size_t)r * 64 * 2688 + s * 32, lq + r * 2048);
    __syncthreads();
    s16x8 a[4], bb[4];
#pragma unroll
    for (int f = 0; f < 4; ++f) {
      a[f] = *(const s16x8*)(Ws + (f * 16 + lr) * 32 + lk);
      bb[f] = *(const s16x8*)(Bs + (w * 64 + f * 16 + lr) * 32 + lk);
    }
#pragma unroll
    for (int fm = 0; fm < 4; ++fm)
#pragma unroll
      for (int fn = 0; fn < 4; ++fn)
        acc[fm][fn] = __builtin_amdgcn_mfma_f32_16x16x32_bf16(a[fm], bb[fn], acc[fm][fn], 0, 0, 0);
    __syncthreads();
  }
  int rbase = (lane >> 4) * 4;
#pragma unroll
  for (int fn = 0; fn < 4; ++fn) {
    int bn = bn0 + w * 64 + fn * 16 + lr;
    int b = bn / 4000;
    int n = bn - b * 4000;
    float* gbase = G + (size_t)(b * 10 + t) * 32 * 4096 + n;
#pragma unroll
    for (int fm = 0; fm < 2; ++fm)
#pragma unroll
      for (int r = 0; r < 4; ++r) {
        int c = fm * 16 + rbase + r;
        float v1 = acc[fm][fn][r] + mlp_b[c];
        float v2 = acc[fm + 2][fn][r] + mlp_b[c + 32];
        gbase[(size_t)c * 4096] = tanhf(v1) * (1.0f / (1.0f + __expf(-v2)));
      }
  }
}

// ct1: g6[b][c][n][q] = ct1_b[q] + sum_{l<10} ct1_w[q][l] * G[b][l][c][n]
__global__ void k_ct1(const float* __restrict__ G, const float* __restrict__ ct1_w,
                      const float* __restrict__ ct1_b, float* __restrict__ g6) {
  int idx = blockIdx.x * 256 + threadIdx.x;
  if (idx >= 8 * 32 * 4000) return;
  int n = idx % 4000;
  int c = (idx / 4000) % 32;
  int b = idx / (4000 * 32);
  const float* gp = G + ((size_t)(b * 10) * 32 + c) * 4096 + n;
  float v[10];
#pragma unroll
  for (int l = 0; l < 10; ++l) v[l] = gp[(size_t)l * 32 * 4096];
  float* o = g6 + (size_t)idx * 6;
#pragma unroll
  for (int q = 0; q < 6; ++q) {
    float a = ct1_b[q];
#pragma unroll
    for (int l = 0; l < 10; ++l) a += ct1_w[q * 10 + l] * v[l];
    o[q] = a;
  }
}

// f1[b][t][n] = sum_c c1[c] * g6[b][c][n][t]
__global__ void k_f1(const float* __restrict__ g6, const float* __restrict__ c1,
                     float* __restrict__ f1) {
  int idx = blockIdx.x * 128 + threadIdx.x;
  if (idx >= 8 * 4000) return;
  int n = idx % 4000, b = idx / 4000;
  float acc[6] = {};
  const float* gp = g6 + ((size_t)b * 32 * 4000 + n) * 6;
  for (int c = 0; c < 32; ++c) {
    float wv = c1[c];
    const float* p = gp + (size_t)c * 4000 * 6;
#pragma unroll
    for (int t = 0; t < 6; ++t) acc[t] += wv * p[t];
  }
  for (int t = 0; t < 6; ++t) f1[((size_t)b * 6 + t) * 4000 + n] = acc[t];
}

// f2[b][c][t] = sum_n c2[n] * g6[b][c][n][t]
__global__ void k_f2(const float* __restrict__ g6, const float* __restrict__ c2,
                     float* __restrict__ f2) {
  __shared__ float red[256 * 6];
  int bc = blockIdx.x;
  int tid = threadIdx.x;
  float acc[6] = {};
  const float* gp = g6 + (size_t)bc * 4000 * 6;
  for (int n = tid; n < 4000; n += 256) {
    float wv = c2[n];
#pragma unroll
    for (int t = 0; t < 6; ++t) acc[t] += wv * gp[(size_t)n * 6 + t];
  }
  for (int t = 0; t < 6; ++t) red[tid * 6 + t] = acc[t];
  __syncthreads();
  for (int s = 128; s > 0; s >>= 1) {
    if (tid < s)
      for (int t = 0; t < 6; ++t) red[tid * 6 + t] += red[(tid + s) * 6 + t];
    __syncthreads();
  }
  if (tid < 6) f2[bc * 6 + tid] = red[tid];
}

// m1[b][t][c] += sum over n-chunk of f1[b][t][n] * tat_w[n][c]; grid (48,16)
__global__ void k_m1(const float* __restrict__ f1, const float* __restrict__ tw,
                     float* __restrict__ m1) {
  __shared__ float red[8][32];
  int bt = blockIdx.x;
  int nc = blockIdx.y;
  int tid = threadIdx.x;
  int c = tid & 31, gi = tid >> 5;
  float acc = 0.f;
  const float* fp = f1 + (size_t)bt * 4000 + nc * 250;
  const float* twp = tw + ((size_t)nc * 250) * 32 + c;
  for (int n = gi; n < 250; n += 8) acc += fp[n] * twp[n * 32];
  red[gi][c] = acc;
  __syncthreads();
  if (tid < 32) {
    float s = 0.f;
#pragma unroll
    for (int gg = 0; gg < 8; ++gg) s += red[gg][c];
    atomicAdd(&m1[(size_t)bt * 32 + c], s);
  }
}

// logits -> sigmoid -> tat_v mix -> BN1 -> softmax -> coefs[b][t][q]
__global__ void k_att(const float* __restrict__ m1, const float* __restrict__ f2,
                      const float* __restrict__ bias, const float* __restrict__ tv,
                      const float* __restrict__ g1, const float* __restrict__ b1,
                      float* __restrict__ coefs) {
  __shared__ float sig[48 * 6], lgs[48 * 6], mu[6], iv[6];
  int tid = threadIdx.x;
  int b = tid / 6, t = tid % 6;
  if (tid < 48) {
    for (int s = 0; s < 6; ++s) {
      float a = bias[t * 6 + s];
      for (int c = 0; c < 32; ++c)
        a += m1[((size_t)b * 6 + t) * 32 + c] * f2[((size_t)b * 32 + c) * 6 + s];
      sig[tid * 6 + s] = 1.0f / (1.0f + __expf(-a));
    }
  }
  __syncthreads();
  if (tid < 48) {
    for (int q = 0; q < 6; ++q) {
      float a = 0.f;
      for (int s = 0; s < 6; ++s) a += tv[t * 6 + s] * sig[(b * 6 + s) * 6 + q];
      lgs[tid * 6 + q] = a;
    }
  }
  __syncthreads();
  if (tid < 6) {
    float s = 0, s2 = 0;
    for (int r = 0; r < 48; ++r) { float v = lgs[r * 6 + tid]; s += v; s2 += v * v; }
    float m = s / 48.f;
    mu[tid] = m;
    iv[tid] = rsqrtf(s2 / 48.f - m * m + 1e-5f);
  }
  __syncthreads();
  if (tid < 48) {
    float v[6], mx = -1e30f;
    for (int q = 0; q < 6; ++q) {
      v[q] = (lgs[tid * 6 + q] - mu[q]) * iv[q] * g1[q] + b1[q];
      mx = fmaxf(mx, v[q]);
    }
    float s = 0;
    for (int q = 0; q < 6; ++q) { v[q] = __expf(v[q] - mx); s += v[q]; }
    float inv = 1.0f / s;
    for (int q = 0; q < 6; ++q) coefs[tid * 6 + q] = v[q] * inv;
  }
}

// y = attention-mix(g6) + conv1(x)[...,6:] -> out (pre-BN2)
__global__ void k_final1(const float* __restrict__ x, const float* __restrict__ cw,
                         const float* __restrict__ cb, const float* __restrict__ g6,
                         const float* __restrict__ coefs, float* __restrict__ out) {
  __shared__ float xt[32 * 8 * 6];
  __shared__ float cwT[1024];
  __shared__ float cfs[36], cbs[32];
  int n0 = blockIdx.x * 8;
  int b = blockIdx.y;
  int tid = threadIdx.x;
  {
    int ci = tid >> 3, seg = tid & 7;
    const float* xp = x + ((size_t)(b * 32 + ci) * 4000 + n0 + seg) * 12 + 6;
#pragma unroll
    for (int q = 0; q < 6; ++q) xt[(ci * 8 + seg) * 6 + q] = xp[q];
  }
  for (int i = tid; i < 1024; i += 256) { int o = i >> 5, ci = i & 31; cwT[ci * 32 + o] = cw[i]; }
  if (tid < 36) cfs[tid] = coefs[b * 36 + tid];
  if (tid < 32) cbs[tid] = cb[tid];
  __syncthreads();
  int nn = tid & 7, c = tid >> 3;
  const float* gp = g6 + ((size_t)(b * 32 + c) * 4000 + n0 + nn) * 6;
  float gv[6];
#pragma unroll
  for (int l = 0; l < 6; ++l) gv[l] = gp[l];
  float y[6];
#pragma unroll
  for (int q = 0; q < 6; ++q) {
    float at = 0.f;
#pragma unroll
    for (int l = 0; l < 6; ++l) at += gv[l] * cfs[q * 6 + l];
    y[q] = at + cbs[c];
  }
  for (int ci = 0; ci < 32; ++ci) {
    float wv = cwT[ci * 32 + c];
#pragma unroll
    for (int q = 0; q < 6; ++q) y[q] += wv * xt[(ci * 8 + nn) * 6 + q];
  }
  float* op = out + ((size_t)(b * 32 + c) * 4000 + n0 + nn) * 6;
#pragma unroll
  for (int q = 0; q < 6; ++q) op[q] = y[q];
}

// per-channel sum/sumsq of out: grid (4, 256), f32x4 + shfl reduce + atomicAdd
__global__ void k_stats(const float* __restrict__ out, float* __restrict__ stats) {
  __shared__ float r1[4], r2[4];
  int bc = blockIdx.y;
  int c = bc & 31;
  int tid = threadIdx.x;
  const float* p = out + (size_t)bc * 24000 + blockIdx.x * 6000;
  float s = 0.f, s2 = 0.f;
  for (int i = tid * 4; i < 6000; i += 1024) {
    f32x4 v = *(const f32x4*)(p + i);
    s  += v.x + v.y + v.z + v.w;
    s2 += v.x * v.x + v.y * v.y + v.z * v.z + v.w * v.w;
  }
#pragma unroll
  for (int off = 32; off > 0; off >>= 1) {
    s  += __shfl_down(s, off);
    s2 += __shfl_down(s2, off);
  }
  int lane = tid & 63, w = tid >> 6;
  if (lane == 0) { r1[w] = s; r2[w] = s2; }
  __syncthreads();
  if (tid == 0) {
    atomicAdd(&stats[c],      r1[0] + r1[1] + r1[2] + r1[3]);
    atomicAdd(&stats[32 + c], r2[0] + r2[1] + r2[2] + r2[3]);
  }
}

__global__ void k_final2(float* __restrict__ out, const float* __restrict__ stats,
                         const float* __restrict__ g2, const float* __restrict__ b2) {
  int idx = (blockIdx.x * 256 + threadIdx.x) * 4;
  if (idx >= 6144000) return;
  int c = (idx / 24000) % 32;
  float mean = stats[c] * (1.0f / 192000.f);
  float var = stats[32 + c] * (1.0f / 192000.f) - mean * mean;
  float sc = rsqrtf(var + 1e-5f) * g2[c];
  float sh = b2[c] - mean * sc;
  f32x4 v = *(f32x4*)(out + idx);
  v.x = v.x * sc + sh; v.y = v.y * sc + sh; v.z = v.z * sc + sh; v.w = v.w * sc + sh;
  *(f32x4*)(out + idx) = v;
}

// ---------------------------------------------------------------------------
extern "C" void kernel_launch(void* const* d_in, const int* in_sizes, int n_in,
                              void* d_out, int out_size, void* d_ws, size_t ws_size,
                              hipStream_t stream) {
  (void)in_sizes; (void)n_in; (void)out_size;
  const float* x       = (const float*)d_in[0];
  const float* A[3]    = {(const float*)d_in[1], (const float*)d_in[2], (const float*)d_in[3]};
  const float* conv1_w = (const float*)d_in[4];
  const float* conv1_b = (const float*)d_in[5];
  const float* mlp_w   = (const float*)d_in[6];
  const float* mlp_b   = (const float*)d_in[7];
  const float* ct1_w   = (const float*)d_in[8];
  const float* ct1_b   = (const float*)d_in[9];
  const float* c1w     = (const float*)d_in[10];
  const float* c2w     = (const float*)d_in[11];
  const float* tw      = (const float*)d_in[12];
  const float* tbias   = (const float*)d_in[13];
  const float* tv      = (const float*)d_in[14];
  const float* bn1g    = (const float*)d_in[15];
  const float* bn1b    = (const float*)d_in[16];
  const float* bn2g    = (const float*)d_in[17];
  const float* bn2b    = (const float*)d_in[18];
  float* out = (float*)d_out;

  char* ws = (char*)d_ws;
  size_t off = 0;
  auto alloc = [&](size_t bytes) { size_t r = off; off += (bytes + 255) & ~(size_t)255; return r; };
  size_t oScat = alloc(172032000);   // [32000*12][224] bf16
  size_t oXt   = alloc(25165824);    // [3072][4096] bf16 ; later g6 (24.576MB f32)
  size_t oA    = alloc(33554432);    // Abf [4096][4096] bf16 ; with oY1t, later G
  size_t oY1t  = alloc(25165824);    // [3072][4096] bf16
  size_t oWcat = alloc(86016);
  size_t oF1 = alloc(768000);
  size_t oF2 = alloc(6144);
  size_t oM1 = alloc(6144);
  size_t oCf = alloc(1152);
  size_t oSt = alloc(256);
  if (ws_size < off) return;  // insufficient scratch -> visible validation failure

  unsigned short* Scat = (unsigned short*)(ws + oScat);
  unsigned short* Xt   = (unsigned short*)(ws + oXt);
  float*          g6   = (float*)(ws + oXt);
  unsigned short* Abf  = (unsigned short*)(ws + oA);
  float*          G    = (float*)(ws + oA);
  unsigned short* Y1t  = (unsigned short*)(ws + oY1t);
  unsigned short* Wcat = (unsigned short*)(ws + oWcat);

  hipMemsetAsync(Xt, 0, 25165824, stream);       // v-padding 4000..4095 must be 0
  hipMemsetAsync(ws + oSt, 0, 256, stream);      // stats accumulators
  hipMemsetAsync(ws + oM1, 0, 6144, stream);     // m1 accumulators
  k_transpose<<<dim3(125, 8), 256, 0, stream>>>(x, Xt, Scat);
  k_wcat<<<168, 256, 0, stream>>>(mlp_w, Wcat);
  for (int i = 0; i < 3; ++i) {
    k_castA<<<16384, 256, 0, stream>>>(A[i], Abf);
    // Y1t[col][node] = sum_v Xt[col][v]*Abf[node][v]; Scat j=2i+1
    k_gemm<0><<<768, 256, 0, stream>>>(Xt, Abf, Y1t, Scat, (2 * i + 1) * 32);
    // x2[node][col] = sum_v Abf[node][v]*Y1t[col][v]; Scat j=2i+2
    k_gemm<1><<<768, 256, 0, stream>>>(Abf, Y1t, nullptr, Scat, (2 * i + 2) * 32);
  }
  k_mlp<<<dim3(125, 10), 256, 0, stream>>>(Wcat, Scat, mlp_b, G);
  k_ct1<<<4000, 256, 0, stream>>>(G, ct1_w, ct1_b, g6);
  k_f1<<<250, 128, 0, stream>>>(g6, c1w, (float*)(ws + oF1));
  k_f2<<<256, 256, 0, stream>>>(g6, c2w, (float*)(ws + oF2));
  k_m1<<<dim3(48, 16), 256, 0, stream>>>((float*)(ws + oF1), tw, (float*)(ws + oM1));
  k_att<<<1, 64, 0, stream>>>((float*)(ws + oM1), (float*)(ws + oF2), tbias, tv, bn1g, bn1b,
                              (float*)(ws + oCf));
  k_final1<<<dim3(500, 8), 256, 0, stream>>>(x, conv1_w, conv1_b, g6, (float*)(ws + oCf), out);
  k_stats<<<dim3(4, 256), 256, 0, stream>>>(out, (float*)(ws + oSt));
  k_final2<<<6000, 256, 0, stream>>>(out, (float*)(ws + oSt), bn2g, bn2b);
}